// Round 4
// baseline (288.730 us; speedup 1.0000x reference)
//
#include <hip/hip_runtime.h>
#include <hip/hip_fp16.h>
#include <math.h>

typedef _Float16 f16;
typedef _Float16 f16x8 __attribute__((ext_vector_type(8)));
typedef _Float16 f16x4v __attribute__((ext_vector_type(4)));
typedef float f32x16 __attribute__((ext_vector_type(16)));

#define B_SZ 16384
#define D_INP 128
#define HID 2048
#define DIMS 9
#define OUTC 54   // DIM*(N_BASIS+1)
#define OUTP 64   // padded to MFMA tile
#define NZ3 4     // split-K factor for GEMM3

// ---------------- async global->LDS (16B per lane, wave-uniform LDS base) ----
__device__ __forceinline__ void load_lds16(const f16* g, f16* l) {
    __builtin_amdgcn_global_load_lds(
        (__attribute__((address_space(1))) void*)(g),
        (__attribute__((address_space(3))) void*)(l),
        16, 0, 0);
}

__device__ __forceinline__ float fast_tanh(float x) {
    // tanh(x) = 1 - 2/(exp(2x)+1); exp via v_exp_f32 (exp2)
    float e = __builtin_amdgcn_exp2f(2.885390081777927f * x);  // e^(2x)
    return 1.0f - 2.0f * __builtin_amdgcn_rcpf(e + 1.0f);
}

// ---------------- fused fp32 -> fp16 converts (input, W0, W1, Wl-pad) -------
#define N4_INP (B_SZ * D_INP / 4)      // 524288
#define N4_W0  (HID * D_INP / 4)       // 65536
#define N4_W1  (HID * HID / 4)         // 1048576
#define N4_WL  (OUTP * HID / 4)        // 32768
__global__ __launch_bounds__(256) void cvt_fused_kernel(
    const float* __restrict__ input, const float* __restrict__ W0,
    const float* __restrict__ W1, const float* __restrict__ Wl,
    f16* __restrict__ inp16, f16* __restrict__ w0q,
    f16* __restrict__ w1q, f16* __restrict__ wlq)
{
    int i = blockIdx.x * 256 + threadIdx.x;
    const float* s; f16* d; int j;
    if (i < N4_INP) { s = input; d = inp16; j = i; }
    else if (i < N4_INP + N4_W0) { s = W0; d = w0q; j = i - N4_INP; }
    else if (i < N4_INP + N4_W0 + N4_W1) { s = W1; d = w1q; j = i - N4_INP - N4_W0; }
    else {
        // Wl pad: dest (64 x 2048), source (54 x 2048)
        j = i - N4_INP - N4_W0 - N4_W1;
        int e0 = j * 4, row = e0 >> 11, col = e0 & (HID - 1);
        f16x4v o;
        if (row < OUTC) {
            float4 v = ((const float4*)Wl)[(row * HID + col) >> 2];
            o.x = (f16)v.x; o.y = (f16)v.y; o.z = (f16)v.z; o.w = (f16)v.w;
        } else {
            o.x = (f16)0.f; o.y = (f16)0.f; o.z = (f16)0.f; o.w = (f16)0.f;
        }
        ((f16x4v*)wlq)[j] = o;
        return;
    }
    float4 v = ((const float4*)s)[j];
    f16x4v o;
    o.x = (f16)v.x; o.y = (f16)v.y; o.z = (f16)v.z; o.w = (f16)v.w;
    ((f16x4v*)d)[j] = o;
}

// ---------------- NT GEMM: C = A(MxK) * B(NxK)^T, fp16 in / fp32 acc -------
// 32x32x16 MFMA; BK=64 (128B LDS rows); 16B-chunk c of row r at slot c^(r&7).
// Block swizzle: groups of 8 m-tiles x all n-tiles for L2 locality.
// EPI 0: C_f16 = tanh(acc + bias[col])                       (stride N)
// EPI 1: partial slice z: C[z*M*N + row*N+col] = acc*100 (+bias*100 on z==0)
template <int BN, int EPI>
__global__ __launch_bounds__(256, 2) void gemm_nt(
    const f16* __restrict__ A, const f16* __restrict__ Bm,
    const float* __restrict__ bias, void* __restrict__ Cout,
    int M, int N, int K, int bias_n)
{
    constexpr int BM = 128, BK = 64;
    constexpr int NI = BN / 64;                 // 32-col subtiles per wave
    __shared__ __align__(16) f16 sa[BM * BK];
    __shared__ __align__(16) f16 sb[BN * BK];

    const int tid  = threadIdx.x;
    const int lane = tid & 63;
    const int wave = tid >> 6;
    const int wm = wave >> 1, wn = wave & 1;

    // L2-locality block swizzle: 8 m-tiles per group, n fastest within group
    const int flat = blockIdx.x + blockIdx.y * gridDim.x;
    const int gsz  = 8 * gridDim.y;
    const int grp  = flat / gsz;
    const int rem  = flat - grp * gsz;
    const int m0 = (grp * 8 + (rem & 7)) * BM;
    const int n0 = (rem >> 3) * BN;

    const int k_len = K / gridDim.z;
    const int k_beg = blockIdx.z * k_len;
    const int k_end = k_beg + k_len;

    f32x16 acc[2][NI];
    #pragma unroll
    for (int i = 0; i < 2; ++i)
        #pragma unroll
        for (int j = 0; j < NI; ++j)
            #pragma unroll
            for (int r = 0; r < 16; ++r) acc[i][j][r] = 0.f;

    const int r8 = lane >> 3;                        // row within 8-row staging group
    const int cg = (((lane & 7) ^ r8) << 3);         // swizzled global k-chunk (elems)

    for (int k0 = k_beg; k0 < k_end; k0 += BK) {
        #pragma unroll
        for (int c = 0; c < (BM * BK * 2) / 4096; ++c) {
            int o = c * 4096 + wave * 1024;          // wave-uniform LDS byte base
            const f16* gp = A + (size_t)(m0 + (o >> 7) + r8) * K + k0 + cg;
            load_lds16(gp, (f16*)((char*)sa + o));
        }
        #pragma unroll
        for (int c = 0; c < (BN * BK * 2) / 4096; ++c) {
            int o = c * 4096 + wave * 1024;
            const f16* gp = Bm + (size_t)(n0 + (o >> 7) + r8) * K + k0 + cg;
            load_lds16(gp, (f16*)((char*)sb + o));
        }
        __syncthreads();   // drains vmcnt (global_load_lds) + barrier

        #pragma unroll
        for (int kc = 0; kc < 4; ++kc) {
            const int ch = kc * 2 + (lane >> 5);     // global 16B-chunk index for this frag
            f16x8 af[2], bf[NI];
            #pragma unroll
            for (int mi = 0; mi < 2; ++mi) {
                int ar = wm * 64 + mi * 32 + (lane & 31);
                af[mi] = *(const f16x8*)&sa[ar * 64 + ((ch ^ (ar & 7)) << 3)];
            }
            #pragma unroll
            for (int ni = 0; ni < NI; ++ni) {
                int br = wn * (BN / 2) + ni * 32 + (lane & 31);
                bf[ni] = *(const f16x8*)&sb[br * 64 + ((ch ^ (br & 7)) << 3)];
            }
            #pragma unroll
            for (int mi = 0; mi < 2; ++mi)
                #pragma unroll
                for (int ni = 0; ni < NI; ++ni)
                    acc[mi][ni] = __builtin_amdgcn_mfma_f32_32x32x16_f16(af[mi], bf[ni], acc[mi][ni], 0, 0, 0);
        }
        __syncthreads();   // protect LDS before next stage
    }

    // epilogue: 32x32 C/D layout col = lane&31, row = (reg&3)+8*(reg>>2)+4*(lane>>5)
    const int crow_b = m0 + wm * 64 + 4 * (lane >> 5);
    const int ccol0 = n0 + wn * (BN / 2) + (lane & 31);
    if (EPI == 0) {
        f16* C = (f16*)Cout;
        #pragma unroll
        for (int mi = 0; mi < 2; ++mi)
            #pragma unroll
            for (int ni = 0; ni < NI; ++ni) {
                int col = ccol0 + ni * 32;
                float bv = bias[col];
                #pragma unroll
                for (int r = 0; r < 16; ++r) {
                    int row = crow_b + mi * 32 + (r & 3) + 8 * (r >> 2);
                    float v = fast_tanh(acc[mi][ni][r] + bv);
                    C[(size_t)row * N + col] = (f16)v;
                }
            }
    } else {
        float* C = (float*)Cout + (size_t)blockIdx.z * M * N;
        #pragma unroll
        for (int mi = 0; mi < 2; ++mi)
            #pragma unroll
            for (int ni = 0; ni < NI; ++ni) {
                int col = ccol0 + ni * 32;
                float bv = (blockIdx.z == 0 && col < bias_n) ? bias[col] * 100.0f : 0.0f;
                #pragma unroll
                for (int r = 0; r < 16; ++r) {
                    int row = crow_b + mi * 32 + (r & 3) + 8 * (r >> 2);
                    float v = acc[mi][ni][r] * 100.0f + bv;
                    C[(size_t)row * N + col] = v;
                }
            }
    }
}

// ---------------- DMP Euler integration (sums NZ3 partial slices) -----------
// out3p: (NZ3, B, 64) partial MLP outputs; input: (B, 128); out: (B, 9, 10)
__global__ __launch_bounds__(256) void integrate_kernel(
    const float* __restrict__ out3p, const float* __restrict__ input,
    float* __restrict__ out)
{
    __shared__ float g[500];
    {
        int k = threadIdx.x;
        if (k < 100) {
            // x after k+1 steps of x *= 0.99  (closed form)
            float x = expf(-0.010050335853501441f * (float)(k + 1));
            float psi[5], ssum = 0.0f;
            #pragma unroll
            for (int n = 0; n < 5; ++n) {
                float c = expf(-0.25f * (float)n);
                float h = 11.180339887498949f / c;   // N^1.5 / c / A_X
                float dx = x - c;
                psi[n] = expf(-h * dx * dx);
                ssum += psi[n];
            }
            float inv = x / ssum;
            #pragma unroll
            for (int n = 0; n < 5; ++n) g[k * 5 + n] = psi[n] * inv;
        }
    }
    __syncthreads();

    int r = blockIdx.x * 256 + threadIdx.x;      // 0 .. B*9-1
    int b = r / DIMS, d = r - b * DIMS;

    float goal = 0.f, w0 = 0.f, w1 = 0.f, w2 = 0.f, w3 = 0.f, w4 = 0.f;
    #pragma unroll
    for (int z = 0; z < NZ3; ++z) {
        const float* ob = out3p + (size_t)z * B_SZ * OUTP + (size_t)b * OUTP;
        goal += ob[d];
        w0 += ob[DIMS + d * 5 + 0];
        w1 += ob[DIMS + d * 5 + 1];
        w2 += ob[DIMS + d * 5 + 2];
        w3 += ob[DIMS + d * 5 + 3];
        w4 += ob[DIMS + d * 5 + 4];
    }

    float y = input[(size_t)b * D_INP + 7 + d];    // y0
    float z = input[(size_t)b * D_INP + 22 + d];   // dy0 * TAU (TAU=1)
    const float scale = goal - y;

    float prev = y;
    float* op = out + (size_t)b * (DIMS * 10) + d * 10;
    int j = 0;
    for (int k = 0; k < 100; ++k) {
        const float* gk = &g[k * 5];
        float fx = scale * (w0 * gk[0] + w1 * gk[1] + w2 * gk[2] + w3 * gk[3] + w4 * gk[4]);
        float dz = 25.0f * (6.25f * (goal - y) - z) + fx;   // A_Z=25, B_Z=6.25
        y = y + z * 0.01f;     // dy = z (old z), y += dy*DT
        z = z + dz * 0.01f;
        if ((k % 10) == 9) { op[j] = y - prev; prev = y; ++j; }
    }
}

// ---------------- launch ----------------
extern "C" void kernel_launch(void* const* d_in, const int* in_sizes, int n_in,
                              void* d_out, int out_size, void* d_ws, size_t ws_size,
                              hipStream_t stream) {
    (void)in_sizes; (void)n_in; (void)out_size; (void)ws_size;
    const float* input = (const float*)d_in[0];
    const float* W0 = (const float*)d_in[1];
    const float* b0 = (const float*)d_in[2];
    const float* W1 = (const float*)d_in[3];
    const float* b1 = (const float*)d_in[4];
    const float* Wl = (const float*)d_in[5];
    const float* bl = (const float*)d_in[6];
    float* out = (float*)d_out;

    // workspace layout (all 16B-aligned by construction)
    f16* inp16 = (f16*)d_ws;                              // 16384*128
    f16* w0q = inp16 + (size_t)B_SZ * D_INP;              // 2048*128
    f16* w1q = w0q + (size_t)HID * D_INP;                 // 2048*2048
    f16* wlq = w1q + (size_t)HID * HID;                   // 64*2048
    f16* h1  = wlq + (size_t)OUTP * HID;                  // 16384*2048
    f16* h2  = h1 + (size_t)B_SZ * HID;                   // 16384*2048
    // GEMM3 partial slices overlay h1 (dead after GEMM2): NZ3 * 16384 * 64 f32
    float* out3p = (float*)h1;

    int n4_total = N4_INP + N4_W0 + N4_W1 + N4_WL;
    cvt_fused_kernel<<<(n4_total + 255) / 256, 256, 0, stream>>>(
        input, W0, W1, Wl, inp16, w0q, w1q, wlq);

    // h1 = tanh(input @ W0^T + b0)
    gemm_nt<128, 0><<<dim3(B_SZ / 128, HID / 128, 1), 256, 0, stream>>>(
        inp16, w0q, b0, (void*)h1, B_SZ, HID, D_INP, HID);
    // h2 = tanh(h1 @ W1^T + b1)
    gemm_nt<128, 0><<<dim3(B_SZ / 128, HID / 128, 1), 256, 0, stream>>>(
        h1, w1q, b1, (void*)h2, B_SZ, HID, HID, HID);
    // out3p[z] = (h2 @ Wl^T)*100 slices (+bl*100 on z0); N padded to 64
    gemm_nt<64, 1><<<dim3(B_SZ / 128, 1, NZ3), 256, 0, stream>>>(
        h2, wlq, bl, (void*)out3p, B_SZ, OUTP, HID, OUTC);

    integrate_kernel<<<B_SZ * DIMS / 256, 256, 0, stream>>>(out3p, input, out);
}

// Round 5
// 256.797 us; speedup vs baseline: 1.1244x; 1.1244x over previous
//
#include <hip/hip_runtime.h>
#include <hip/hip_fp16.h>
#include <math.h>

typedef _Float16 f16;
typedef _Float16 f16x8 __attribute__((ext_vector_type(8)));
typedef _Float16 f16x4v __attribute__((ext_vector_type(4)));
typedef float f32x4 __attribute__((ext_vector_type(4)));

#define B_SZ 16384
#define D_INP 128
#define HID 2048
#define DIMS 9
#define OUTC 54   // DIM*(N_BASIS+1)
#define OUTP 64   // padded to MFMA tile
#define NZ3 4     // split-K factor for GEMM3

// ---------------- async global->LDS (16B per lane, wave-uniform LDS base) ----
__device__ __forceinline__ void load_lds16(const f16* g, f16* l) {
    __builtin_amdgcn_global_load_lds(
        (__attribute__((address_space(1))) void*)(g),
        (__attribute__((address_space(3))) void*)(l),
        16, 0, 0);
}

__device__ __forceinline__ float fast_tanh(float x) {
    // tanh(x) = 1 - 2/(exp(2x)+1); exp via v_exp_f32 (exp2)
    float e = __builtin_amdgcn_exp2f(2.885390081777927f * x);  // e^(2x)
    return 1.0f - 2.0f * __builtin_amdgcn_rcpf(e + 1.0f);
}

// ---------------- fused fp32 -> fp16 converts (W0, W1, Wl-pad) --------------
#define N4_W0  (HID * D_INP / 4)       // 65536
#define N4_W1  (HID * HID / 4)         // 1048576
#define N4_WL  (OUTP * HID / 4)        // 32768
// total = 1146880 = 256 * 4480 exactly (no tail threads)
__global__ __launch_bounds__(256) void cvt_fused_kernel(
    const float* __restrict__ W0, const float* __restrict__ W1,
    const float* __restrict__ Wl,
    f16* __restrict__ w0q, f16* __restrict__ w1q, f16* __restrict__ wlq)
{
    int i = blockIdx.x * 256 + threadIdx.x;
    const float* s; f16* d; int j;
    if (i < N4_W0) { s = W0; d = w0q; j = i; }
    else if (i < N4_W0 + N4_W1) { s = W1; d = w1q; j = i - N4_W0; }
    else {
        // Wl pad: dest (64 x 2048), source (54 x 2048)
        j = i - N4_W0 - N4_W1;
        int e0 = j * 4, row = e0 >> 11, col = e0 & (HID - 1);
        f16x4v o;
        if (row < OUTC) {
            float4 v = ((const float4*)Wl)[(row * HID + col) >> 2];
            o.x = (f16)v.x; o.y = (f16)v.y; o.z = (f16)v.z; o.w = (f16)v.w;
        } else {
            o.x = (f16)0.f; o.y = (f16)0.f; o.z = (f16)0.f; o.w = (f16)0.f;
        }
        ((f16x4v*)wlq)[j] = o;
        return;
    }
    float4 v = ((const float4*)s)[j];
    f16x4v o;
    o.x = (f16)v.x; o.y = (f16)v.y; o.z = (f16)v.z; o.w = (f16)v.w;
    ((f16x4v*)d)[j] = o;
}

// ---------------- NT GEMM: C = A(MxK) * B(NxK)^T, fp16 in / fp32 acc -------
// 16x16x32 MFMA; BK=64 (128B LDS rows); 16B-chunk c of row r at slot c^(r&7).
// Conflict-free law (R3 vs R4 measured): row-XOR swizzle + chunk index varying
// per QUARTER-wave (lane>>4) => 0 conflicts. Half-wave chunk (32x32 layout)
// conflicts (1.68e7). Keep 16x16x32.
// Block swizzle: groups of 8 m-tiles x all n-tiles for L2 locality.
// EPI 0: C_f16 = tanh(acc + bias[col])                       (stride N)
// EPI 1: partial slice z: C[z*M*N + row*N+col] = acc*100 (+bias*100 on z==0)
template <int BN, int EPI>
__global__ __launch_bounds__(256, 2) void gemm_nt(
    const f16* __restrict__ A, const f16* __restrict__ Bm,
    const float* __restrict__ bias, void* __restrict__ Cout,
    int M, int N, int K, int bias_n)
{
    constexpr int BM = 128, BK = 64;
    constexpr int NI = BN / 32;                 // 16-col subtiles per wave
    __shared__ __align__(16) f16 sa[BM * BK];
    __shared__ __align__(16) f16 sb[BN * BK];

    const int tid  = threadIdx.x;
    const int lane = tid & 63;
    const int wave = tid >> 6;
    const int wm = wave >> 1, wn = wave & 1;

    // L2-locality block swizzle: 8 m-tiles per group, n fastest within group
    const int flat = blockIdx.x + blockIdx.y * gridDim.x;
    const int gsz  = 8 * gridDim.y;
    const int grp  = flat / gsz;
    const int rem  = flat - grp * gsz;
    const int m0 = (grp * 8 + (rem & 7)) * BM;
    const int n0 = (rem >> 3) * BN;

    const int k_len = K / gridDim.z;
    const int k_beg = blockIdx.z * k_len;
    const int k_end = k_beg + k_len;

    f32x4 acc[4][NI];
    #pragma unroll
    for (int i = 0; i < 4; ++i)
        #pragma unroll
        for (int j = 0; j < NI; ++j) acc[i][j] = (f32x4){0.f, 0.f, 0.f, 0.f};

    const int r8 = lane >> 3;                        // row within 8-row staging group
    const int cg = (((lane & 7) ^ r8) << 3);         // swizzled global k-chunk (elems)

    for (int k0 = k_beg; k0 < k_end; k0 += BK) {
        #pragma unroll
        for (int c = 0; c < (BM * BK * 2) / 4096; ++c) {
            int o = c * 4096 + wave * 1024;          // wave-uniform LDS byte base
            const f16* gp = A + (size_t)(m0 + (o >> 7) + r8) * K + k0 + cg;
            load_lds16(gp, (f16*)((char*)sa + o));
        }
        #pragma unroll
        for (int c = 0; c < (BN * BK * 2) / 4096; ++c) {
            int o = c * 4096 + wave * 1024;
            const f16* gp = Bm + (size_t)(n0 + (o >> 7) + r8) * K + k0 + cg;
            load_lds16(gp, (f16*)((char*)sb + o));
        }
        __syncthreads();   // drains vmcnt (global_load_lds) + barrier

        #pragma unroll
        for (int kc = 0; kc < 2; ++kc) {
            f16x8 af[4], bf[NI];
            #pragma unroll
            for (int mi = 0; mi < 4; ++mi) {
                int ar = wm * 64 + mi * 16 + (lane & 15);
                af[mi] = *(const f16x8*)&sa[ar * 64 + ((((kc << 2) | (lane >> 4)) ^ (ar & 7)) << 3)];
            }
            #pragma unroll
            for (int ni = 0; ni < NI; ++ni) {
                int br = wn * (BN / 2) + ni * 16 + (lane & 15);
                bf[ni] = *(const f16x8*)&sb[br * 64 + ((((kc << 2) | (lane >> 4)) ^ (br & 7)) << 3)];
            }
            #pragma unroll
            for (int mi = 0; mi < 4; ++mi)
                #pragma unroll
                for (int ni = 0; ni < NI; ++ni)
                    acc[mi][ni] = __builtin_amdgcn_mfma_f32_16x16x32_f16(af[mi], bf[ni], acc[mi][ni], 0, 0, 0);
        }
        __syncthreads();   // protect LDS before next stage
    }

    // epilogue: C/D layout col = lane&15, row = (lane>>4)*4 + r
    const int crow0 = m0 + wm * 64 + (lane >> 4) * 4;
    const int ccol0 = n0 + wn * (BN / 2) + (lane & 15);
    if (EPI == 0) {
        f16* C = (f16*)Cout;
        #pragma unroll
        for (int mi = 0; mi < 4; ++mi)
            #pragma unroll
            for (int ni = 0; ni < NI; ++ni) {
                int col = ccol0 + ni * 16;
                float bv = bias[col];
                #pragma unroll
                for (int r2 = 0; r2 < 4; ++r2) {
                    float v = fast_tanh(acc[mi][ni][r2] + bv);
                    C[(size_t)(crow0 + mi * 16 + r2) * N + col] = (f16)v;
                }
            }
    } else {
        float* C = (float*)Cout + (size_t)blockIdx.z * M * N;
        #pragma unroll
        for (int mi = 0; mi < 4; ++mi)
            #pragma unroll
            for (int ni = 0; ni < NI; ++ni) {
                int col = ccol0 + ni * 16;
                float bv = (blockIdx.z == 0 && col < bias_n) ? bias[col] * 100.0f : 0.0f;
                #pragma unroll
                for (int r2 = 0; r2 < 4; ++r2) {
                    float v = acc[mi][ni][r2] * 100.0f + bv;
                    C[(size_t)(crow0 + mi * 16 + r2) * N + col] = v;
                }
            }
    }
}

// ---------------- GEMM1: A is fp32 (raw input), staged with in-reg convert ---
// C_f16 = tanh(A(16384x128_f32) @ W0q(2048x128_f16)^T + b0); K = 128 (2 iters)
__global__ __launch_bounds__(256, 2) void gemm1_f32a(
    const float* __restrict__ A, const f16* __restrict__ Bm,
    const float* __restrict__ bias, f16* __restrict__ C)
{
    constexpr int BM = 128, BK = 64, BN = 128, NI = 4;
    constexpr int N = HID, K = D_INP;
    __shared__ __align__(16) f16 sa[BM * BK];
    __shared__ __align__(16) f16 sb[BN * BK];

    const int tid  = threadIdx.x;
    const int lane = tid & 63;
    const int wave = tid >> 6;
    const int wm = wave >> 1, wn = wave & 1;

    const int flat = blockIdx.x + blockIdx.y * gridDim.x;
    const int gsz  = 8 * gridDim.y;
    const int grp  = flat / gsz;
    const int rem  = flat - grp * gsz;
    const int m0 = (grp * 8 + (rem & 7)) * BM;
    const int n0 = (rem >> 3) * BN;

    f32x4 acc[4][NI];
    #pragma unroll
    for (int i = 0; i < 4; ++i)
        #pragma unroll
        for (int j = 0; j < NI; ++j) acc[i][j] = (f32x4){0.f, 0.f, 0.f, 0.f};

    const int r8 = lane >> 3;
    const int cg = (((lane & 7) ^ r8) << 3);

    for (int k0 = 0; k0 < K; k0 += BK) {
        // A: fp32 global -> convert -> ds_write_b128 (lane-contiguous, conflict-free)
        #pragma unroll
        for (int c = 0; c < (BM * BK * 2) / 4096; ++c) {
            int o = c * 4096 + wave * 1024;
            const float* gp = A + (size_t)(m0 + (o >> 7) + r8) * K + k0 + cg;
            float4 v0 = *(const float4*)gp;
            float4 v1 = *(const float4*)(gp + 4);
            f16x8 h;
            h[0] = (f16)v0.x; h[1] = (f16)v0.y; h[2] = (f16)v0.z; h[3] = (f16)v0.w;
            h[4] = (f16)v1.x; h[5] = (f16)v1.y; h[6] = (f16)v1.z; h[7] = (f16)v1.w;
            *(f16x8*)((char*)sa + o + (lane << 4)) = h;
        }
        // B: pre-converted f16 via async DMA
        #pragma unroll
        for (int c = 0; c < (BN * BK * 2) / 4096; ++c) {
            int o = c * 4096 + wave * 1024;
            const f16* gp = Bm + (size_t)(n0 + (o >> 7) + r8) * K + k0 + cg;
            load_lds16(gp, (f16*)((char*)sb + o));
        }
        __syncthreads();

        #pragma unroll
        for (int kc = 0; kc < 2; ++kc) {
            f16x8 af[4], bf[NI];
            #pragma unroll
            for (int mi = 0; mi < 4; ++mi) {
                int ar = wm * 64 + mi * 16 + (lane & 15);
                af[mi] = *(const f16x8*)&sa[ar * 64 + ((((kc << 2) | (lane >> 4)) ^ (ar & 7)) << 3)];
            }
            #pragma unroll
            for (int ni = 0; ni < NI; ++ni) {
                int br = wn * 64 + ni * 16 + (lane & 15);
                bf[ni] = *(const f16x8*)&sb[br * 64 + ((((kc << 2) | (lane >> 4)) ^ (br & 7)) << 3)];
            }
            #pragma unroll
            for (int mi = 0; mi < 4; ++mi)
                #pragma unroll
                for (int ni = 0; ni < NI; ++ni)
                    acc[mi][ni] = __builtin_amdgcn_mfma_f32_16x16x32_f16(af[mi], bf[ni], acc[mi][ni], 0, 0, 0);
        }
        __syncthreads();
    }

    const int crow0 = m0 + wm * 64 + (lane >> 4) * 4;
    const int ccol0 = n0 + wn * 64 + (lane & 15);
    #pragma unroll
    for (int mi = 0; mi < 4; ++mi)
        #pragma unroll
        for (int ni = 0; ni < NI; ++ni) {
            int col = ccol0 + ni * 16;
            float bv = bias[col];
            #pragma unroll
            for (int r2 = 0; r2 < 4; ++r2) {
                float v = fast_tanh(acc[mi][ni][r2] + bv);
                C[(size_t)(crow0 + mi * 16 + r2) * N + col] = (f16)v;
            }
        }
}

// ---------------- DMP Euler integration (sums NZ3 partial slices) -----------
// out3p: (NZ3, B, 64) partial MLP outputs; input: (B, 128); out: (B, 9, 10)
__global__ __launch_bounds__(256) void integrate_kernel(
    const float* __restrict__ out3p, const float* __restrict__ input,
    float* __restrict__ out)
{
    __shared__ float g[500];
    {
        int k = threadIdx.x;
        if (k < 100) {
            // x after k+1 steps of x *= 0.99  (closed form)
            float x = expf(-0.010050335853501441f * (float)(k + 1));
            float psi[5], ssum = 0.0f;
            #pragma unroll
            for (int n = 0; n < 5; ++n) {
                float c = expf(-0.25f * (float)n);
                float h = 11.180339887498949f / c;   // N^1.5 / c / A_X
                float dx = x - c;
                psi[n] = expf(-h * dx * dx);
                ssum += psi[n];
            }
            float inv = x / ssum;
            #pragma unroll
            for (int n = 0; n < 5; ++n) g[k * 5 + n] = psi[n] * inv;
        }
    }
    __syncthreads();

    int r = blockIdx.x * 256 + threadIdx.x;      // 0 .. B*9-1
    int b = r / DIMS, d = r - b * DIMS;

    float goal = 0.f, w0 = 0.f, w1 = 0.f, w2 = 0.f, w3 = 0.f, w4 = 0.f;
    #pragma unroll
    for (int z = 0; z < NZ3; ++z) {
        const float* ob = out3p + (size_t)z * B_SZ * OUTP + (size_t)b * OUTP;
        goal += ob[d];
        w0 += ob[DIMS + d * 5 + 0];
        w1 += ob[DIMS + d * 5 + 1];
        w2 += ob[DIMS + d * 5 + 2];
        w3 += ob[DIMS + d * 5 + 3];
        w4 += ob[DIMS + d * 5 + 4];
    }

    float y = input[(size_t)b * D_INP + 7 + d];    // y0
    float z = input[(size_t)b * D_INP + 22 + d];   // dy0 * TAU (TAU=1)
    const float scale = goal - y;

    float prev = y;
    float* op = out + (size_t)b * (DIMS * 10) + d * 10;
    int j = 0;
    for (int k = 0; k < 100; ++k) {
        const float* gk = &g[k * 5];
        float fx = scale * (w0 * gk[0] + w1 * gk[1] + w2 * gk[2] + w3 * gk[3] + w4 * gk[4]);
        float dz = 25.0f * (6.25f * (goal - y) - z) + fx;   // A_Z=25, B_Z=6.25
        y = y + z * 0.01f;     // dy = z (old z), y += dy*DT
        z = z + dz * 0.01f;
        if ((k % 10) == 9) { op[j] = y - prev; prev = y; ++j; }
    }
}

// ---------------- launch ----------------
extern "C" void kernel_launch(void* const* d_in, const int* in_sizes, int n_in,
                              void* d_out, int out_size, void* d_ws, size_t ws_size,
                              hipStream_t stream) {
    (void)in_sizes; (void)n_in; (void)out_size; (void)ws_size;
    const float* input = (const float*)d_in[0];
    const float* W0 = (const float*)d_in[1];
    const float* b0 = (const float*)d_in[2];
    const float* W1 = (const float*)d_in[3];
    const float* b1 = (const float*)d_in[4];
    const float* Wl = (const float*)d_in[5];
    const float* bl = (const float*)d_in[6];
    float* out = (float*)d_out;

    // workspace layout (all 16B-aligned by construction)
    f16* w0q = (f16*)d_ws;                                // 2048*128
    f16* w1q = w0q + (size_t)HID * D_INP;                 // 2048*2048
    f16* wlq = w1q + (size_t)HID * HID;                   // 64*2048
    f16* h1  = wlq + (size_t)OUTP * HID;                  // 16384*2048
    f16* h2  = h1 + (size_t)B_SZ * HID;                   // 16384*2048
    // GEMM3 partial slices overlay h1 (dead after GEMM2): NZ3 * 16384 * 64 f32
    float* out3p = (float*)h1;

    int n4_total = N4_W0 + N4_W1 + N4_WL;
    cvt_fused_kernel<<<(n4_total + 255) / 256, 256, 0, stream>>>(
        W0, W1, Wl, w0q, w1q, wlq);

    // h1 = tanh(input @ W0^T + b0), A staged from fp32 directly
    gemm1_f32a<<<dim3(B_SZ / 128, HID / 128), 256, 0, stream>>>(
        input, w0q, b0, h1);
    // h2 = tanh(h1 @ W1^T + b1)
    gemm_nt<128, 0><<<dim3(B_SZ / 128, HID / 128, 1), 256, 0, stream>>>(
        h1, w1q, b1, (void*)h2, B_SZ, HID, HID, HID);
    // out3p[z] = (h2 @ Wl^T)*100 slices (+bl*100 on z0); N padded to 64
    gemm_nt<64, 1><<<dim3(B_SZ / 128, 1, NZ3), 256, 0, stream>>>(
        h2, wlq, bl, (void*)out3p, B_SZ, OUTP, HID, OUTC);

    integrate_kernel<<<B_SZ * DIMS / 256, 256, 0, stream>>>(out3p, input, out);
}